// Round 4
// baseline (604.532 us; speedup 1.0000x reference)
//
#include <hip/hip_runtime.h>
#include <hip/hip_fp16.h>
#include <hip/hip_bf16.h>

#define CI 16
#define CO 48
#define DD 31
#define HH 256
#define WW 256
#define SP (HH*WW)          // 65536
#define CHUNK (DD*SP)       // 2031616 elems per channel
#define NTP 14              // 28 tap-slots (27 real + 1 zero pad), 2 taps per k-step

typedef __bf16 bf16x8 __attribute__((ext_vector_type(8)));
typedef float  f32x4  __attribute__((ext_vector_type(4)));

// ---------------- weight prep: w[co][ci][dz][ky][kx] -> wB{h,l}[tp][co][tl*16+ci] (bf16 split)
__global__ void wprep_kernel(const float* __restrict__ w,
                             ushort* __restrict__ wBh,
                             ushort* __restrict__ wBl) {
    int id = blockIdx.x * 256 + threadIdx.x;          // NTP*CO*32 = 21504
    if (id >= NTP * CO * 32) return;
    int tp = id / (CO * 32);
    int r  = id % (CO * 32);
    int co = r / 32;
    int kk = r % 32;
    int tl = kk >> 4, ci = kk & 15;
    int tap = tp * 2 + tl;
    float v = (tap < 27) ? w[co * 432 + ci * 27 + tap] : 0.f;
    uint u = __builtin_bit_cast(uint, v);
    uint hbits = (u + 0x7FFFu + ((u >> 16) & 1)) >> 16;
    float hf = __builtin_bit_cast(float, hbits << 16);
    float lres = v - hf;
    uint ul = __builtin_bit_cast(uint, lres);
    uint lbits = (ul + 0x7FFFu + ((ul >> 16) & 1)) >> 16;
    wBh[id] = (ushort)hbits;
    wBl[id] = (ushort)lbits;
}

// ---------------- conv 3x3x3 (16->48) implicit-GEMM MFMA, 2 depths per block
// block: 256 thr = 4 waves; tile 16x16 pixels at depths d0,d0+1; wave wv owns rows 4wv..4wv+3.
// LDS x: [slice 4][yy 18][cihalf 2][xx 18][8ci] bf16; granule = 16B; ds_read_b128 conflict-free.
__global__ __launch_bounds__(256, 3)
void conv_kernel(const float* __restrict__ x,
                 const ushort* __restrict__ wBh,
                 const ushort* __restrict__ wBl,
                 const float* __restrict__ b,
                 float* __restrict__ zout,
                 __half* __restrict__ f1out,
                 __half* __restrict__ f2out)
{
    __shared__ __align__(16) ushort xs[4 * 18 * 2 * 18 * 8];   // 41472 B

    const int tid = threadIdx.x;
    const int d0  = blockIdx.z * 2;
    const int y0  = blockIdx.y * 16;
    const int x0  = blockIdx.x * 16;

    // ---- stage 4 depth-slices of the x tile as bf16 ----
    for (int t = tid; t < 4 * 18 * 18 * 2; t += 256) {
        int dz = t / 648;                      // slice 0..3 -> depth d0-1+dz
        int r1 = t - dz * 648;
        int yy = r1 / 36;
        int r2 = r1 - yy * 36;
        int xx = r2 >> 1;
        int hf = r2 & 1;                       // ci half
        int gd = d0 + dz - 1;
        int gh = y0 + yy - 1;
        int gw = x0 + xx - 1;
        uint4 q;
        uint vv[8];
        if ((unsigned)gd < DD && (unsigned)gh < HH && (unsigned)gw < WW) {
            const float* xp = x + ((size_t)(hf * 8) * DD + gd) * SP + gh * WW + gw;
            #pragma unroll
            for (int j = 0; j < 8; ++j) {
                float f = xp[(size_t)j * DD * SP];
                uint u = __builtin_bit_cast(uint, f);
                vv[j] = (u + 0x7FFFu + ((u >> 16) & 1)) >> 16;    // RNE bf16
            }
        } else {
            #pragma unroll
            for (int j = 0; j < 8; ++j) vv[j] = 0;
        }
        q.x = vv[0] | (vv[1] << 16);
        q.y = vv[2] | (vv[3] << 16);
        q.z = vv[4] | (vv[5] << 16);
        q.w = vv[6] | (vv[7] << 16);
        int g = ((dz * 18 + yy) * 2 + hf) * 18 + xx;
        *(uint4*)(xs + (size_t)g * 8) = q;
    }
    __syncthreads();

    const int lane   = tid & 63;
    const int wv     = tid >> 6;
    const int xl     = lane & 15;
    const int hq     = lane >> 4;       // 0..3
    const int tl     = hq >> 1;         // tap-in-pair
    const int cihalf = hq & 1;          // ci half

    f32x4 acc[2][4][3];
    #pragma unroll
    for (int dd = 0; dd < 2; ++dd)
        #pragma unroll
        for (int m = 0; m < 4; ++m)
            #pragma unroll
            for (int g = 0; g < 3; ++g)
                acc[dd][m][g] = (f32x4){0.f, 0.f, 0.f, 0.f};

    const int boff = xl * 32 + 8 * hq;        // lane part of B offset

    uint4 bh[3], bl[3];
    #pragma unroll
    for (int g = 0; g < 3; ++g) {
        bh[g] = *(const uint4*)(wBh + g * 512 + boff);
        bl[g] = *(const uint4*)(wBl + g * 512 + boff);
    }

    #pragma unroll 1
    for (int tp = 0; tp < NTP; ++tp) {
        uint4 bh2[3], bl2[3];
        if (tp < NTP - 1) {
            #pragma unroll
            for (int g = 0; g < 3; ++g) {
                bh2[g] = *(const uint4*)(wBh + (tp + 1) * 1536 + g * 512 + boff);
                bl2[g] = *(const uint4*)(wBl + (tp + 1) * 1536 + g * 512 + boff);
            }
        }

        int tap = tp * 2 + tl;
        if (tap > 26) tap = 26;          // pad slot: B is zero there
        int dz = tap / 9;
        int rr = tap - dz * 9;
        int ky = rr / 3;
        int kx = rr - ky * 3;
        const int arow = 4 * wv + ky;
        const int acol = xl + kx;

        #pragma unroll
        for (int dd = 0; dd < 2; ++dd) {
            #pragma unroll
            for (int m = 0; m < 4; ++m) {
                int abase = ((((dz + dd) * 18 + (arow + m)) * 2 + cihalf) * 18 + acol) * 8;
                uint4 aq = *(const uint4*)(xs + abase);
                bf16x8 a = __builtin_bit_cast(bf16x8, aq);
                #pragma unroll
                for (int g = 0; g < 3; ++g) {
                    acc[dd][m][g] = __builtin_amdgcn_mfma_f32_16x16x32_bf16(
                        a, __builtin_bit_cast(bf16x8, bh[g]), acc[dd][m][g], 0, 0, 0);
                    acc[dd][m][g] = __builtin_amdgcn_mfma_f32_16x16x32_bf16(
                        a, __builtin_bit_cast(bf16x8, bl[g]), acc[dd][m][g], 0, 0, 0);
                }
            }
        }
        if (tp < NTP - 1) {
            #pragma unroll
            for (int g = 0; g < 3; ++g) { bh[g] = bh2[g]; bl[g] = bl2[g]; }
        }
    }

    // ---- epilogue: C/D: channel = lane&15, pixel x = 4*hq + r
    const int c   = xl;
    const float bz  = b[c];
    const float bf1 = b[16 + c];
    const float bf2 = b[32 + c];

    #pragma unroll
    for (int dd = 0; dd < 2; ++dd) {
        const int d = d0 + dd;
        if (d >= DD) continue;
        #pragma unroll
        for (int m = 0; m < 4; ++m) {
            const int gy = y0 + 4 * wv + m;
            const int gx = x0 + hq * 4;
            const size_t base = ((size_t)c * DD + d) * SP + gy * WW + gx;
            float4 zq;
            union { __half hh[4]; uint2 u; } p1, p2;
            #pragma unroll
            for (int r = 0; r < 4; ++r) {
                float g0 = acc[dd][m][0][r] + bz;
                float g1 = acc[dd][m][1][r] + bf1;
                float g2 = acc[dd][m][2][r] + bf2;
                float z  = 1.f - 2.f / (__expf(2.f * g0) + 1.f);
                float f1 = 1.f / (1.f + __expf(-g1));
                float f2 = 1.f / (1.f + __expf(-g2));
                ((float*)&zq)[r] = z;
                p1.hh[r] = __float2half(f1);
                p2.hh[r] = __float2half(f2);
            }
            *(float4*)(zout + base) = zq;
            *(uint2*)((ushort*)f1out + base) = p1.u;
            *(uint2*)((ushort*)f2out + base) = p2.u;
        }
    }
}

// ---------------- bidirectional depth scan; 2 columns per thread
// zin aliases out (d_out) -- same thread reads & writes its own columns only.
__global__ __launch_bounds__(256, 4)
void scan_kernel(const float* zin,
                 const __half* __restrict__ f1in,
                 const __half* __restrict__ f2in,
                 float* out) {
    const int id = blockIdx.x * 256 + threadIdx.x;   // 0 .. 16*32768-1
    const int c  = id >> 15;
    const int p2 = id & 32767;
    const size_t base = (size_t)c * CHUNK + (size_t)p2 * 2;

    float2 z[DD];
    uint hsp[DD];
    float hx = 0.f, hy = 0.f;
    #pragma unroll
    for (int d = 0; d < DD; ++d) {
        const size_t o = base + (size_t)d * SP;
        float2 zz = *(const float2*)(zin + o);
        __half2 f = *(const __half2*)(f1in + o);
        float fx = __half2float(f.x), fy = __half2float(f.y);
        hx = fx * hx + (1.f - fx) * zz.x;
        hy = fy * hy + (1.f - fy) * zz.y;
        z[d] = zz;
        __half2 hp; hp.x = __float2half(hx); hp.y = __float2half(hy);
        hsp[d] = __builtin_bit_cast(uint, hp);
    }
    float rx = 0.f, ry = 0.f;
    #pragma unroll
    for (int d = DD - 1; d >= 0; --d) {
        const size_t o = base + (size_t)d * SP;
        __half2 f = *(const __half2*)(f2in + o);
        float fx = __half2float(f.x), fy = __half2float(f.y);
        rx = fx * rx + (1.f - fx) * z[d].x;
        ry = fy * ry + (1.f - fy) * z[d].y;
        __half2 hp = __builtin_bit_cast(__half2, hsp[d]);
        float2 ov;
        ov.x = __half2float(hp.x) + rx;
        ov.y = __half2float(hp.y) + ry;
        *(float2*)(out + o) = ov;
    }
}

extern "C" void kernel_launch(void* const* d_in, const int* in_sizes, int n_in,
                              void* d_out, int out_size, void* d_ws, size_t ws_size,
                              hipStream_t stream) {
    const float* x = (const float*)d_in[0];
    const float* w = (const float*)d_in[1];
    const float* b = (const float*)d_in[2];
    float* out = (float*)d_out;

    char* ws = (char*)d_ws;
    const size_t half_elems = (size_t)CHUNK * 16;        // 32,505,856
    __half* f1  = (__half*)ws;
    __half* f2  = (__half*)(ws + half_elems * sizeof(__half));
    ushort* wBh = (ushort*)(ws + 2 * half_elems * sizeof(__half));
    ushort* wBl = wBh + NTP * CO * 32;
    // ws requirement: 130,023,424 + 2*43,008 B ~= 130.1 MB

    wprep_kernel<<<(NTP * CO * 32 + 255) / 256, 256, 0, stream>>>(w, wBh, wBl);

    dim3 grid(WW / 16, HH / 16, (DD + 1) / 2);
    conv_kernel<<<grid, 256, 0, stream>>>(x, wBh, wBl, b, out, f1, f2);

    scan_kernel<<<(16 * SP / 2) / 256, 256, 0, stream>>>(out, f1, f2, out);
}

// Round 6
// 554.575 us; speedup vs baseline: 1.0901x; 1.0901x over previous
//
#include <hip/hip_runtime.h>
#include <hip/hip_fp16.h>
#include <hip/hip_bf16.h>

#define CI 16
#define CO 48
#define DD 31
#define HH 256
#define WW 256
#define SP (HH*WW)          // 65536
#define CHUNK (DD*SP)       // 2031616 elems per channel
#define NTP 14              // 28 tap-slots (27 real + 1 zero pad), 2 taps per k-step

// padded bf16 x: [34][258][258][16] (depth pad 1 front + 2 back, h/w pad 1 each side)
#define PD 34
#define PH 258
#define PW 258
#define XTP_ELEMS ((size_t)PD*PH*PW*16)
#define DSTRIDE (PH*PW*16)       // 1,065,024 elems per depth slice
#define YSTRIDE (PW*16)          // 4,128 elems per row

typedef __bf16 bf16x8 __attribute__((ext_vector_type(8)));
typedef float  f32x4  __attribute__((ext_vector_type(4)));

// ---------------- weight prep: w[co][ci][dz][ky][kx] -> wB{h,l}[tp][co][tl*16+ci] (bf16 split)
__global__ void wprep_kernel(const float* __restrict__ w,
                             ushort* __restrict__ wBh,
                             ushort* __restrict__ wBl) {
    int id = blockIdx.x * 256 + threadIdx.x;          // NTP*CO*32 = 21504
    if (id >= NTP * CO * 32) return;
    int tp = id / (CO * 32);
    int r  = id % (CO * 32);
    int co = r / 32;
    int kk = r % 32;
    int tl = kk >> 4, ci = kk & 15;
    int tap = tp * 2 + tl;
    float v = (tap < 27) ? w[co * 432 + ci * 27 + tap] : 0.f;
    uint u = __builtin_bit_cast(uint, v);
    uint hbits = (u + 0x7FFFu + ((u >> 16) & 1)) >> 16;
    float hf = __builtin_bit_cast(float, hbits << 16);
    float lres = v - hf;
    uint ul = __builtin_bit_cast(uint, lres);
    uint lbits = (ul + 0x7FFFu + ((ul >> 16) & 1)) >> 16;
    wBh[id] = (ushort)hbits;
    wBl[id] = (ushort)lbits;
}

// ---------------- x prep: fp32 NCDHW -> padded bf16 [dp][hp][wp][ci]
__global__ __launch_bounds__(256)
void xprep_kernel(const float* __restrict__ x, ushort* __restrict__ xT) {
    int id = blockIdx.x * 256 + threadIdx.x;
    if (id >= PH * PW) return;
    int dp = blockIdx.y;
    int hp = id / PW;
    int wp = id - hp * PW;
    int d = dp - 1, h = hp - 1, w = wp - 1;
    ushort* o = xT + ((size_t)(dp * PH + hp) * PW + wp) * 16;
    uint4 q0 = {0,0,0,0}, q1 = {0,0,0,0};
    if ((unsigned)d < DD && (unsigned)h < HH && (unsigned)w < WW) {
        const float* xp = x + (size_t)d * SP + h * WW + w;
        uint vv[16];
        #pragma unroll
        for (int ci = 0; ci < 16; ++ci) {
            float f = xp[(size_t)ci * CHUNK];
            uint u = __builtin_bit_cast(uint, f);
            vv[ci] = (u + 0x7FFFu + ((u >> 16) & 1)) >> 16;   // RNE bf16
        }
        q0.x = vv[0] | (vv[1] << 16);  q0.y = vv[2]  | (vv[3] << 16);
        q0.z = vv[4] | (vv[5] << 16);  q0.w = vv[6]  | (vv[7] << 16);
        q1.x = vv[8] | (vv[9] << 16);  q1.y = vv[10] | (vv[11] << 16);
        q1.z = vv[12]| (vv[13] << 16); q1.w = vv[14] | (vv[15] << 16);
    }
    *(uint4*)o = q0;
    *(uint4*)(o + 8) = q1;
}

// ---------------- conv via implicit-GEMM MFMA, direct-global A reads from padded bf16 xT
// block: 256 thr = 4 waves; 16x16 pixel tile at depths d0,d0+1; wave wv owns rows 4wv..4wv+3.
// No LDS, no barriers, no bounds checks (padding absorbs halo).
__global__ __launch_bounds__(256, 3)
void conv_kernel_xt(const ushort* __restrict__ xT,
                    const ushort* __restrict__ wBh,
                    const ushort* __restrict__ wBl,
                    const float* __restrict__ b,
                    float* __restrict__ zout,
                    __half* __restrict__ f1out,
                    __half* __restrict__ f2out)
{
    // XCD-aware bijective swizzle: 4096 blocks, 8 XCDs, 512-chunks (2 depth-layers each)
    int bl = blockIdx.x + (blockIdx.y << 4) + (blockIdx.z << 8);
    int nb = ((bl & 7) << 9) | (bl >> 3);
    const int x0 = (nb & 15) * 16;
    const int y0 = ((nb >> 4) & 15) * 16;
    const int d0 = (nb >> 8) * 2;

    const int tid  = threadIdx.x;
    const int lane = tid & 63;
    const int wv   = tid >> 6;
    const int xl   = lane & 15;
    const int hq   = lane >> 4;       // 0..3
    const int tl   = hq >> 1;         // tap-in-pair
    const int cihalf = hq & 1;        // ci half

    const ushort* lbA = xT + ((size_t)((d0 * PH + (y0 + 4 * wv)) * PW + (x0 + xl)) * 16
                              + cihalf * 8);
    const int boff = xl * 32 + 8 * hq;

    f32x4 acc[2][4][3];
    #pragma unroll
    for (int dd = 0; dd < 2; ++dd)
        #pragma unroll
        for (int m = 0; m < 4; ++m)
            #pragma unroll
            for (int g = 0; g < 3; ++g)
                acc[dd][m][g] = (f32x4){0.f, 0.f, 0.f, 0.f};

    #pragma unroll
    for (int tp = 0; tp < NTP; ++tp) {
        // tap offsets (compile-time under full unroll), tl-select at runtime
        const int tap0 = tp * 2;
        const int tap1 = (tp * 2 + 1 > 26) ? 26 : tp * 2 + 1;
        const int O0 = (tap0 / 9) * DSTRIDE + ((tap0 % 9) / 3) * YSTRIDE + (tap0 % 3) * 16;
        const int O1 = (tap1 / 9) * DSTRIDE + ((tap1 % 9) / 3) * YSTRIDE + (tap1 % 3) * 16;
        const int offt = tl ? O1 : O0;

        uint4 bh[3], blq[3];
        #pragma unroll
        for (int g = 0; g < 3; ++g) {
            bh[g]  = *(const uint4*)(wBh + tp * 1536 + g * 512 + boff);
            blq[g] = *(const uint4*)(wBl + tp * 1536 + g * 512 + boff);
        }

        #pragma unroll
        for (int dd = 0; dd < 2; ++dd) {
            #pragma unroll
            for (int m = 0; m < 4; ++m) {
                uint4 aq = *(const uint4*)(lbA + offt + dd * DSTRIDE + m * YSTRIDE);
                bf16x8 a = __builtin_bit_cast(bf16x8, aq);
                #pragma unroll
                for (int g = 0; g < 3; ++g) {
                    acc[dd][m][g] = __builtin_amdgcn_mfma_f32_16x16x32_bf16(
                        a, __builtin_bit_cast(bf16x8, bh[g]), acc[dd][m][g], 0, 0, 0);
                    acc[dd][m][g] = __builtin_amdgcn_mfma_f32_16x16x32_bf16(
                        a, __builtin_bit_cast(bf16x8, blq[g]), acc[dd][m][g], 0, 0, 0);
                }
            }
        }
    }

    // ---- epilogue: C/D: channel = lane&15, pixel x = 4*hq + r
    const int c   = xl;
    const float bz  = b[c];
    const float bf1 = b[16 + c];
    const float bf2 = b[32 + c];

    #pragma unroll
    for (int dd = 0; dd < 2; ++dd) {
        const int d = d0 + dd;
        if (d >= DD) continue;
        #pragma unroll
        for (int m = 0; m < 4; ++m) {
            const int gy = y0 + 4 * wv + m;
            const int gx = x0 + hq * 4;
            const size_t base = ((size_t)c * DD + d) * SP + gy * WW + gx;
            float4 zq;
            union { __half hh[4]; uint2 u; } p1, p2;
            #pragma unroll
            for (int r = 0; r < 4; ++r) {
                float g0 = acc[dd][m][0][r] + bz;
                float g1 = acc[dd][m][1][r] + bf1;
                float g2 = acc[dd][m][2][r] + bf2;
                float z  = 1.f - 2.f / (__expf(2.f * g0) + 1.f);
                float f1 = 1.f / (1.f + __expf(-g1));
                float f2 = 1.f / (1.f + __expf(-g2));
                ((float*)&zq)[r] = z;
                p1.hh[r] = __float2half(f1);
                p2.hh[r] = __float2half(f2);
            }
            *(float4*)(zout + base) = zq;
            *(uint2*)((ushort*)f1out + base) = p1.u;
            *(uint2*)((ushort*)f2out + base) = p2.u;
        }
    }
}

// ---------------- FALLBACK conv (R4 path, stages fp32 x -> LDS bf16), used if ws too small
__global__ __launch_bounds__(256, 3)
void conv_kernel_fb(const float* __restrict__ x,
                    const ushort* __restrict__ wBh,
                    const ushort* __restrict__ wBl,
                    const float* __restrict__ b,
                    float* __restrict__ zout,
                    __half* __restrict__ f1out,
                    __half* __restrict__ f2out)
{
    __shared__ __align__(16) ushort xs[4 * 18 * 2 * 18 * 8];

    const int tid = threadIdx.x;
    const int d0  = blockIdx.z * 2;
    const int y0  = blockIdx.y * 16;
    const int x0  = blockIdx.x * 16;

    for (int t = tid; t < 4 * 18 * 18 * 2; t += 256) {
        int dz = t / 648;
        int r1 = t - dz * 648;
        int yy = r1 / 36;
        int r2 = r1 - yy * 36;
        int xx = r2 >> 1;
        int hf = r2 & 1;
        int gd = d0 + dz - 1;
        int gh = y0 + yy - 1;
        int gw = x0 + xx - 1;
        uint4 q;
        uint vv[8];
        if ((unsigned)gd < DD && (unsigned)gh < HH && (unsigned)gw < WW) {
            const float* xp = x + ((size_t)(hf * 8) * DD + gd) * SP + gh * WW + gw;
            #pragma unroll
            for (int j = 0; j < 8; ++j) {
                float f = xp[(size_t)j * DD * SP];
                uint u = __builtin_bit_cast(uint, f);
                vv[j] = (u + 0x7FFFu + ((u >> 16) & 1)) >> 16;
            }
        } else {
            #pragma unroll
            for (int j = 0; j < 8; ++j) vv[j] = 0;
        }
        q.x = vv[0] | (vv[1] << 16);
        q.y = vv[2] | (vv[3] << 16);
        q.z = vv[4] | (vv[5] << 16);
        q.w = vv[6] | (vv[7] << 16);
        int g = ((dz * 18 + yy) * 2 + hf) * 18 + xx;
        *(uint4*)(xs + (size_t)g * 8) = q;
    }
    __syncthreads();

    const int lane   = tid & 63;
    const int wv     = tid >> 6;
    const int xl     = lane & 15;
    const int hq     = lane >> 4;
    const int tl     = hq >> 1;
    const int cihalf = hq & 1;

    f32x4 acc[2][4][3];
    #pragma unroll
    for (int dd = 0; dd < 2; ++dd)
        #pragma unroll
        for (int m = 0; m < 4; ++m)
            #pragma unroll
            for (int g = 0; g < 3; ++g)
                acc[dd][m][g] = (f32x4){0.f, 0.f, 0.f, 0.f};

    const int boff = xl * 32 + 8 * hq;

    #pragma unroll 1
    for (int tp = 0; tp < NTP; ++tp) {
        int tap = tp * 2 + tl;
        if (tap > 26) tap = 26;
        int dz = tap / 9;
        int rr = tap - dz * 9;
        int ky = rr / 3;
        int kx = rr - ky * 3;
        const int arow = 4 * wv + ky;
        const int acol = xl + kx;

        uint4 bh[3], blq[3];
        #pragma unroll
        for (int g = 0; g < 3; ++g) {
            bh[g]  = *(const uint4*)(wBh + tp * 1536 + g * 512 + boff);
            blq[g] = *(const uint4*)(wBl + tp * 1536 + g * 512 + boff);
        }

        #pragma unroll
        for (int dd = 0; dd < 2; ++dd) {
            #pragma unroll
            for (int m = 0; m < 4; ++m) {
                int abase = ((((dz + dd) * 18 + (arow + m)) * 2 + cihalf) * 18 + acol) * 8;
                uint4 aq = *(const uint4*)(xs + abase);
                bf16x8 a = __builtin_bit_cast(bf16x8, aq);
                #pragma unroll
                for (int g = 0; g < 3; ++g) {
                    acc[dd][m][g] = __builtin_amdgcn_mfma_f32_16x16x32_bf16(
                        a, __builtin_bit_cast(bf16x8, bh[g]), acc[dd][m][g], 0, 0, 0);
                    acc[dd][m][g] = __builtin_amdgcn_mfma_f32_16x16x32_bf16(
                        a, __builtin_bit_cast(bf16x8, blq[g]), acc[dd][m][g], 0, 0, 0);
                }
            }
        }
    }

    const int c   = xl;
    const float bz  = b[c];
    const float bf1 = b[16 + c];
    const float bf2 = b[32 + c];

    #pragma unroll
    for (int dd = 0; dd < 2; ++dd) {
        const int d = d0 + dd;
        if (d >= DD) continue;
        #pragma unroll
        for (int m = 0; m < 4; ++m) {
            const int gy = y0 + 4 * wv + m;
            const int gx = x0 + hq * 4;
            const size_t base = ((size_t)c * DD + d) * SP + gy * WW + gx;
            float4 zq;
            union { __half hh[4]; uint2 u; } p1, p2;
            #pragma unroll
            for (int r = 0; r < 4; ++r) {
                float g0 = acc[dd][m][0][r] + bz;
                float g1 = acc[dd][m][1][r] + bf1;
                float g2 = acc[dd][m][2][r] + bf2;
                float z  = 1.f - 2.f / (__expf(2.f * g0) + 1.f);
                float f1 = 1.f / (1.f + __expf(-g1));
                float f2 = 1.f / (1.f + __expf(-g2));
                ((float*)&zq)[r] = z;
                p1.hh[r] = __float2half(f1);
                p2.hh[r] = __float2half(f2);
            }
            *(float4*)(zout + base) = zq;
            *(uint2*)((ushort*)f1out + base) = p1.u;
            *(uint2*)((ushort*)f2out + base) = p2.u;
        }
    }
}

// ---------------- bidirectional depth scan; one thread per (c,h,w) column (R3 proven)
// zin aliases out (d_out) -- do NOT mark them restrict.
__global__ __launch_bounds__(256)
void scan_kernel(const float* zin,
                 const __half* __restrict__ f1in,
                 const __half* __restrict__ f2in,
                 float* out) {
    const int id = blockIdx.x * 256 + threadIdx.x;
    const int c = id >> 16;
    const int p = id & (SP - 1);
    const size_t base = (size_t)c * CHUNK + p;

    float z[DD], hs[DD];
    float h = 0.f;
    #pragma unroll
    for (int d = 0; d < DD; ++d) {
        float zz = zin[base + (size_t)d * SP];
        float f  = __half2float(f1in[base + (size_t)d * SP]);
        h = f * h + (1.f - f) * zz;
        z[d] = zz;
        hs[d] = h;
    }
    float hr = 0.f;
    #pragma unroll
    for (int d = DD - 1; d >= 0; --d) {
        float f = __half2float(f2in[base + (size_t)d * SP]);
        hr = f * hr + (1.f - f) * z[d];
        out[base + (size_t)d * SP] = hs[d] + hr;
    }
}

extern "C" void kernel_launch(void* const* d_in, const int* in_sizes, int n_in,
                              void* d_out, int out_size, void* d_ws, size_t ws_size,
                              hipStream_t stream) {
    const float* x = (const float*)d_in[0];
    const float* w = (const float*)d_in[1];
    const float* b = (const float*)d_in[2];
    float* out = (float*)d_out;

    char* ws = (char*)d_ws;
    const size_t half_bytes = (size_t)CHUNK * 16 * sizeof(__half);   // 65,011,712
    const size_t wb_bytes   = (size_t)NTP * CO * 32 * sizeof(ushort);// 43,008
    __half* f1  = (__half*)ws;
    __half* f2  = (__half*)(ws + half_bytes);
    ushort* wBh = (ushort*)(ws + 2 * half_bytes);
    ushort* wBl = (ushort*)(ws + 2 * half_bytes + wb_bytes);
    ushort* xT  = (ushort*)(ws + 2 * half_bytes + 2 * wb_bytes);
    const size_t need = 2 * half_bytes + 2 * wb_bytes + XTP_ELEMS * sizeof(ushort); // ~202.5 MB

    wprep_kernel<<<(NTP * CO * 32 + 255) / 256, 256, 0, stream>>>(w, wBh, wBl);

    dim3 grid(WW / 16, HH / 16, (DD + 1) / 2);
    if (ws_size >= need) {
        dim3 tgrid((PH * PW + 255) / 256, PD, 1);
        xprep_kernel<<<tgrid, 256, 0, stream>>>(x, xT);
        conv_kernel_xt<<<grid, 256, 0, stream>>>(xT, wBh, wBl, b, out, f1, f2);
    } else {
        conv_kernel_fb<<<grid, 256, 0, stream>>>(x, wBh, wBl, b, out, f1, f2);
    }

    scan_kernel<<<(16 * SP) / 256, 256, 0, stream>>>(out, f1, f2, out);
}